// Round 19
// baseline (354.762 us; speedup 1.0000x reference)
//
#include <hip/hip_runtime.h>
#include <hip/hip_bf16.h>

// Problem constants (B=8, C=512, N=4096, heads=8, splits=4)
#define BATCH 8
#define CIN   512
#define NTOK  4096
#define CH    256      // C2 = C/2
#define J3    768      // 3*C2
#define NH    8        // heads
#define DH    32       // head dim
#define NCH   1024     // tokens per chunk (N / SPLITS)

typedef _Float16 F16;
typedef _Float16 f16x8 __attribute__((ext_vector_type(8)));
typedef _Float16 f16x4 __attribute__((ext_vector_type(4)));
typedef _Float16 f16x2 __attribute__((ext_vector_type(2)));
typedef float    f32x4  __attribute__((ext_vector_type(4)));
typedef float    f32x16 __attribute__((ext_vector_type(16)));

// scale * log2(e) = (1/sqrt(32)) * 1.4426950408889634
#define QSCALE 0.25503483f

// Tiled layouts (16B-linear staging everywhere):
//   Wc_t [jb(3)][t(16)][kg(4)][row(256)][8]
//   xt_t [b][nb(32)][t(16)][kg(4)][row(128)][8]
//   We_t [jb(4)][t(8)][kg(4)][row(128)][8]
//   O_t  [b][nb(32)][t(8)][kg(4)][row(128)][8]
//   Qb   [b][n][256]                      (token-major, q prescaled)
//   K_t  [b][h][s][t(16)][kg(4)][nk(64)][8]   (fragment-coalesced)
//   V_t  [b][h][s][t(16)][vg(8)][d(32)][8]    (fragment-coalesced)

// ---------------------------------------------------------------------------
// Kernel 0 (2 j per block, 384 blocks). Writes tiled Wc_t.
// ---------------------------------------------------------------------------
__global__ __launch_bounds__(256) void fuse_weights_kernel(
    const float* __restrict__ Wr, const float* __restrict__ br,
    const float* __restrict__ Wqkv,
    F16* __restrict__ Wc_t, float* __restrict__ bcomb)
{
    const int j0 = blockIdx.x * 2;
    const int tid = threadIdx.x;
    float a00 = 0.f, a01 = 0.f, a10 = 0.f, a11 = 0.f;
    for (int c2 = 0; c2 < CH; ++c2) {
        const float w0 = Wr[c2 * CIN + tid];
        const float w1 = Wr[c2 * CIN + tid + 256];
        const float q0 = Wqkv[c2 * J3 + j0];        // uniform -> s_load
        const float q1 = Wqkv[c2 * J3 + j0 + 1];
        a00 = fmaf(w0, q0, a00);
        a01 = fmaf(w1, q0, a01);
        a10 = fmaf(w0, q1, a10);
        a11 = fmaf(w1, q1, a11);
    }
    const int c0 = tid, c1 = tid + 256;
    const int off0 = (c0 >> 5) * 8192 + ((c0 >> 3) & 3) * 2048 + (c0 & 7);
    const int off1 = (c1 >> 5) * 8192 + ((c1 >> 3) & 3) * 2048 + (c1 & 7);
#pragma unroll
    for (int jj = 0; jj < 2; ++jj) {
        const int j = j0 + jj;
        const float qs = (j < 256) ? QSCALE : 1.0f;
        const int jb = j >> 8, row = j & 255;
        const float v0 = jj ? a10 : a00, v1 = jj ? a11 : a01;
        Wc_t[jb * 131072 + off0 + row * 8] = (F16)(v0 * qs);
        Wc_t[jb * 131072 + off1 + row * 8] = (F16)(v1 * qs);
    }
    if (tid < 2) {
        const int j = j0 + tid;
        const float qs = (j < 256) ? QSCALE : 1.0f;
        float s = 0.f;
        for (int c2 = 0; c2 < CH; ++c2) s = fmaf(Wqkv[c2 * J3 + j], br[c2], s);
        bcomb[j] = s * qs;
    }
}

// ---------------------------------------------------------------------------
// convert We [512][256] f32 -> We_t tiled f16
// ---------------------------------------------------------------------------
__global__ __launch_bounds__(256) void convert_we_kernel(
    const float* __restrict__ We, F16* __restrict__ We_t)
{
    const int i = blockIdx.x * 256 + threadIdx.x;
    const int j = i >> 8, c2 = i & 255;
    We_t[(j >> 7) * 32768 + (c2 >> 5) * 4096 + ((c2 >> 3) & 3) * 1024 +
         (j & 127) * 8 + (c2 & 7)] = (F16)We[i];
}

// ---------------------------------------------------------------------------
// transpose-convert x [B][512][4096] f32 -> xt_t tiled f16
// ---------------------------------------------------------------------------
__global__ __launch_bounds__(256) void transpose_convert_kernel(
    const float* __restrict__ x, F16* __restrict__ xt_t)
{
    const int b = blockIdx.z;
    const int c0 = blockIdx.y * 8;
    const int n = blockIdx.x * 256 + threadIdx.x;

    const float* xb = x + ((size_t)b * CIN + c0) * NTOK + n;
    f16x8 v;
#pragma unroll
    for (int i = 0; i < 8; ++i)
        v[i] = (F16)xb[(size_t)i * NTOK];

    const int nb = n >> 7, row = n & 127;
    const int t = c0 >> 5, kg = (c0 >> 3) & 3;
    *(f16x8*)&xt_t[(size_t)b * 2097152 + nb * 65536 + t * 4096 + kg * 1024 +
                   row * 8] = v;
}

// ---------------------------------------------------------------------------
// GEMM1 (unchanged): 256j x 128n tile, 512 thr, tiled linear staging.
// Epilogues write attn-native layouts: jb=0 -> Qb, jb=1 -> K_t, jb=2 -> V_t.
// ---------------------------------------------------------------------------
__global__ __launch_bounds__(512, 4) void gemm1_kernel(
    const F16* __restrict__ A,      // Wc_t tiled
    const F16* __restrict__ B,      // xt_t tiled
    const float* __restrict__ bias, // bcomb [768]
    F16* __restrict__ Qb,           // [B][4096][256]
    F16* __restrict__ Kt,           // [B][8][4][16][4][64][8]
    F16* __restrict__ Vt)           // [B][8][4][16][8][32][8]
{
    const int b  = blockIdx.z;
    const int jb = blockIdx.y;                // 0..2
    const int j0 = jb * 256;
    const int nb = blockIdx.x;                // 0..31
    const int n0 = nb * 128;
    const int tid = threadIdx.x;
    const int w = tid >> 6, l = tid & 63;
    const int wr = w >> 1;          // 0..3 : j-wave
    const int wc = w & 1;           // 0..1 : n-wave
    const int cl = l & 15, rg = l >> 4;

    __shared__ __align__(16) char smem[49152];
    F16* Ash0 = (F16*)smem;
    F16* Ash1 = (F16*)(smem + 16384);
    F16* Bsh0 = (F16*)(smem + 32768);
    F16* Bsh1 = (F16*)(smem + 40960);
    F16* Esh  = (F16*)smem;

    f32x4 acc[4][4];
#pragma unroll
    for (int i = 0; i < 4; ++i)
#pragma unroll
        for (int j = 0; j < 4; ++j) acc[i][j] = (f32x4){0.f, 0.f, 0.f, 0.f};

    const F16* Abase = A + jb * 131072 + tid * 8;
    const F16* Bbase = B + (size_t)b * 2097152 + nb * 65536 + tid * 8;

#define G1_STAGE(Adst, Bdst, t)                                                \
    do {                                                                       \
        __builtin_amdgcn_global_load_lds(                                      \
            (const __attribute__((address_space(1))) void*)(Abase + (t) * 8192),\
            (__attribute__((address_space(3))) void*)&Adst[tid * 8], 16, 0, 0);\
        __builtin_amdgcn_global_load_lds(                                      \
            (const __attribute__((address_space(1))) void*)(Abase + (t) * 8192 \
                + 4096),                                                       \
            (__attribute__((address_space(3))) void*)&Adst[4096 + tid * 8],    \
            16, 0, 0);                                                         \
        __builtin_amdgcn_global_load_lds(                                      \
            (const __attribute__((address_space(1))) void*)(Bbase + (t) * 4096),\
            (__attribute__((address_space(3))) void*)&Bdst[tid * 8], 16, 0, 0);\
    } while (0)

    G1_STAGE(Ash0, Bsh0, 0);
    __syncthreads();

    for (int t = 0; t < 16; ++t) {
        F16* Ac = (t & 1) ? Ash1 : Ash0;
        F16* Bc = (t & 1) ? Bsh1 : Bsh0;
        if (t < 15) {
            F16* An = (t & 1) ? Ash0 : Ash1;
            F16* Bn = (t & 1) ? Bsh0 : Bsh1;
            G1_STAGE(An, Bn, t + 1);
        }
        f16x8 bf[4];
#pragma unroll
        for (int j = 0; j < 4; ++j)
            bf[j] = *(const f16x8*)&Bc[rg * 1024 + (wc * 64 + j * 16 + cl) * 8];
#pragma unroll
        for (int i = 0; i < 4; ++i) {
            const f16x8 af =
                *(const f16x8*)&Ac[rg * 2048 + (wr * 64 + i * 16 + cl) * 8];
#pragma unroll
            for (int j = 0; j < 4; ++j)
                acc[i][j] = __builtin_amdgcn_mfma_f32_16x16x32_f16(
                    af, bf[j], acc[i][j], 0, 0, 0);
        }
        __syncthreads();
    }
#undef G1_STAGE

    const int sidx = n0 >> 10;          // chunk (constant per block)
    const int tb   = (n0 >> 6) & 15;    // tile base within chunk

    if (jb < 2) {
        // ---- Q/K retile: Esh [nl 32][jl 256+8=264]
        const size_t bN = (size_t)b * NTOK;
#pragma unroll
        for (int c = 0; c < 4; ++c) {
            if (c) __syncthreads();
            if (wc == (c >> 1)) {
#pragma unroll
                for (int i = 0; i < 4; ++i) {
#pragma unroll
                    for (int jj = 0; jj < 2; ++jj) {
                        const int jn = (c & 1) * 2 + jj;
                        const int nl = jj * 16 + cl;
                        const int jl = wr * 64 + i * 16 + rg * 4;
                        const int jg = j0 + jl;
                        f16x4 v;
#pragma unroll
                        for (int r = 0; r < 4; ++r)
                            v[r] = (F16)(acc[i][jn][r] + bias[jg + r]);
                        *(f16x4*)&Esh[nl * 264 + jl] = v;
                    }
                }
            }
            __syncthreads();
            if (jb == 0) {
                // Qb token-major: rows of 256 F16
                const int rr = tid >> 4, ss = tid & 15;
                const f16x8 ov0 = *(const f16x8*)&Esh[rr * 264 + ss * 16];
                const f16x8 ov1 = *(const f16x8*)&Esh[rr * 264 + ss * 16 + 8];
                F16* dst = &Qb[(bN + n0 + c * 32 + rr) * 256 + ss * 16];
                *(f16x8*)dst = ov0;
                *(f16x8*)(dst + 8) = ov1;
            } else {
                // K_t: unit (hh, kg, nl) of 8 F16; nk = (c&1)*32+nl
                const int tloc = (tb + (c >> 1)) & 15;
#pragma unroll
                for (int p = 0; p < 2; ++p) {
                    const int uid = tid + p * 512;
                    const int nl = uid & 31, kg = (uid >> 5) & 3,
                              hh = uid >> 7;
                    const f16x8 ov =
                        *(const f16x8*)&Esh[nl * 264 + hh * 32 + kg * 8];
                    const int nk = (c & 1) * 32 + nl;
                    *(f16x8*)&Kt[(((size_t)b * NH + hh) * 4 + sidx) * 32768 +
                                 tloc * 2048 + kg * 512 + nk * 8] = ov;
                }
            }
        }
    } else {
        // ---- V retile (transposed): Esh [jl 64][nn 136]
#pragma unroll
        for (int c = 0; c < 4; ++c) {
            if (c) __syncthreads();
            if (wr == c) {
#pragma unroll
                for (int i = 0; i < 4; ++i) {
                    const int jg = j0 + c * 64 + i * 16 + rg * 4;
#pragma unroll
                    for (int jn = 0; jn < 4; ++jn) {
                        const int nl = wc * 64 + jn * 16 + cl;
#pragma unroll
                        for (int r = 0; r < 4; ++r)
                            Esh[(i * 16 + rg * 4 + r) * 136 + nl] =
                                (F16)(acc[i][jn][r] + bias[jg + r]);
                    }
                }
            }
            __syncthreads();
            // V_t: unit (hl, ttv, vg, d) of 8 F16 (e = nk&7 contiguous)
#pragma unroll
            for (int p = 0; p < 2; ++p) {
                const int uid = tid + p * 512;
                const int d = uid & 31, vg = (uid >> 5) & 7,
                          ttv = (uid >> 8) & 1, hl = uid >> 9;
                const int hh = c * 2 + hl;
                const int tloc = (tb + ttv) & 15;
                const f16x8 ov =
                    *(const f16x8*)&Esh[(hl * 32 + d) * 136 + ttv * 64 + vg * 8];
                *(f16x8*)&Vt[(((size_t)b * NH + hh) * 4 + sidx) * 32768 +
                             tloc * 2048 + vg * 256 + d * 8] = ov;
            }
        }
    }
}

// ---------------------------------------------------------------------------
// MFMA attention R19: ZERO LDS staging, ZERO barriers. K/V fragments load
// DIRECTLY from the tiled K_t/V_t (fragment-coalesced: 512B contiguous per
// instruction -- fixes R10's 64-line failure mode). Waves fully independent;
// LDS only for the per-wave epilogue retile (no __syncthreads anywhere).
// 64 q-rows/wave, VALU f16-tree denominator (R16/R18-proven).
// ---------------------------------------------------------------------------
__global__ __launch_bounds__(256, 8) void attn_mfma_kernel(
    const F16* __restrict__ Qb,   // [B][4096][256] (q prescaled)
    const F16* __restrict__ Kt,   // [B][8][4][16][4][64][8]
    const F16* __restrict__ Vt,   // [B][8][4][16][8][32][8]
    F16* __restrict__ O)          // O_t tiled [b][nb][t][kg][row][8]
{
    const int bid = blockIdx.x;
    const int xcd = bid & 7, tt = bid >> 3;
    const int qpair = tt & 3;               // 0..3 (pair of 128-row blocks)
    const int pr = xcd * 32 + (tt >> 2);    // 0..255
    const int s = pr & 3, bh = pr >> 2;
    const int b = bh >> 3, h = bh & 7;
    const int tid = threadIdx.x;
    const int w = tid >> 6, l = tid & 63;
    const int ln = l & 31;          // q-col (QK) / d-col (PV)
    const int hi = l >> 5;

    __shared__ __align__(16) F16 Epi[4][1152];    // per-wave [32 q][36]
    __shared__ __align__(16) float Ltab_s[4][64]; // per-wave lsum table

    const size_t bN = (size_t)b * NTOK + (size_t)s * NCH;
    const int q0 = qpair * 256 + w * 64;    // wave's 64 q-rows

    // Q B-frags for both sets (d 0-15 / 16-31), prescaled in GEMM1
    const F16* Qpa = Qb + (bN + q0 + ln) * 256 + h * DH + hi * 8;
    const F16* Qpb = Qpa + 32 * 256;
    const f16x8 qfa0 = *(const f16x8*)Qpa;
    const f16x8 qfa1 = *(const f16x8*)(Qpa + 16);
    const f16x8 qfb0 = *(const f16x8*)Qpb;
    const f16x8 qfb1 = *(const f16x8*)(Qpb + 16);

    // direct fragment bases (tiled, fragment-coalesced)
    const F16* Kb = Kt + (((size_t)b * NH + h) * 4 + s) * 32768;
    const F16* Vb = Vt + (((size_t)b * NH + h) * 4 + s) * 32768;

    f32x16 oacca = (f32x16)(0.0f);
    f32x16 oaccb = (f32x16)(0.0f);
    float lsum_a = 0.f, lsum_b = 0.f;

    for (int t = 0; t < 16; ++t) {
#pragma unroll
        for (int u = 0; u < 2; ++u) {
            // K A-frags: kf0 at kg=hi, kf1 at kg=2+hi; row nk = u*32+ln
            const f16x8 kf0 =
                *(const f16x8*)&Kb[t * 2048 + hi * 512 + (u * 32 + ln) * 8];
            const f16x8 kf1 =
                *(const f16x8*)&Kb[t * 2048 + (2 + hi) * 512 + (u * 32 + ln) * 8];

            // ---- set a: QK -> exp2 -> pkrtz -> lsum tree
            f32x16 sacc = (f32x16)(0.0f);
            __builtin_amdgcn_s_setprio(1);
            sacc = __builtin_amdgcn_mfma_f32_32x32x16_f16(kf0, qfa0, sacc, 0, 0, 0);
            sacc = __builtin_amdgcn_mfma_f32_32x32x16_f16(kf1, qfa1, sacc, 0, 0, 0);
            __builtin_amdgcn_s_setprio(0);
            union { f16x8 v; f16x2 h[4]; } pa0, pa1, pb0, pb1;
#pragma unroll
            for (int e = 0; e < 4; ++e) {
                pa0.h[e] = __builtin_bit_cast(f16x2, __builtin_amdgcn_cvt_pkrtz(
                    __builtin_amdgcn_exp2f(sacc[2 * e]),
                    __builtin_amdgcn_exp2f(sacc[2 * e + 1])));
                pa1.h[e] = __builtin_bit_cast(f16x2, __builtin_amdgcn_cvt_pkrtz(
                    __builtin_amdgcn_exp2f(sacc[8 + 2 * e]),
                    __builtin_amdgcn_exp2f(sacc[8 + 2 * e + 1])));
            }
            {
                const f16x2 t01 = pa0.h[0] + pa0.h[1] + pa1.h[0] + pa1.h[1];
                const f16x2 t23 = pa0.h[2] + pa0.h[3] + pa1.h[2] + pa1.h[3];
                const f16x2 ts = t01 + t23;
                lsum_a += (float)ts[0] + (float)ts[1];
            }

            // ---- set b: QK -> exp2 -> pkrtz -> lsum tree
            f32x16 sb = (f32x16)(0.0f);
            __builtin_amdgcn_s_setprio(1);
            sb = __builtin_amdgcn_mfma_f32_32x32x16_f16(kf0, qfb0, sb, 0, 0, 0);
            sb = __builtin_amdgcn_mfma_f32_32x32x16_f16(kf1, qfb1, sb, 0, 0, 0);
            __builtin_amdgcn_s_setprio(0);
#pragma unroll
            for (int e = 0; e < 4; ++e) {
                pb0.h[e] = __builtin_bit_cast(f16x2, __builtin_amdgcn_cvt_pkrtz(
                    __builtin_amdgcn_exp2f(sb[2 * e]),
                    __builtin_amdgcn_exp2f(sb[2 * e + 1])));
                pb1.h[e] = __builtin_bit_cast(f16x2, __builtin_amdgcn_cvt_pkrtz(
                    __builtin_amdgcn_exp2f(sb[8 + 2 * e]),
                    __builtin_amdgcn_exp2f(sb[8 + 2 * e + 1])));
            }
            {
                const f16x2 t01 = pb0.h[0] + pb0.h[1] + pb1.h[0] + pb1.h[1];
                const f16x2 t23 = pb0.h[2] + pb0.h[3] + pb1.h[2] + pb1.h[3];
                const f16x2 ts = t01 + t23;
                lsum_b += (float)ts[0] + (float)ts[1];
            }

            // V B-frags direct from V_t (sigma order): vg = u*4 + {0,1,2,3},
            // each lane reads 8B at [vg][d=ln][e0=4*hi].
            const int vb0 = t * 2048 + (u * 4) * 256 + ln * 8 + 4 * hi;
            const f16x4 v00 = *(const f16x4*)&Vb[vb0];
            const f16x4 v01 = *(const f16x4*)&Vb[vb0 + 256];
            const f16x4 v10 = *(const f16x4*)&Vb[vb0 + 512];
            const f16x4 v11 = *(const f16x4*)&Vb[vb0 + 768];
            const f16x8 vf0 = __builtin_shufflevector(v00, v01, 0, 1, 2, 3, 4, 5, 6, 7);
            const f16x8 vf1 = __builtin_shufflevector(v10, v11, 0, 1, 2, 3, 4, 5, 6, 7);

            __builtin_amdgcn_s_setprio(1);
            oacca = __builtin_amdgcn_mfma_f32_32x32x16_f16(pa0.v, vf0, oacca, 0, 0, 0);
            oacca = __builtin_amdgcn_mfma_f32_32x32x16_f16(pa1.v, vf1, oacca, 0, 0, 0);
            oaccb = __builtin_amdgcn_mfma_f32_32x32x16_f16(pb0.v, vf0, oaccb, 0, 0, 0);
            oaccb = __builtin_amdgcn_mfma_f32_32x32x16_f16(pb1.v, vf1, oaccb, 0, 0, 0);
            __builtin_amdgcn_s_setprio(0);
        }
    }

    // ---- epilogue (per-wave private LDS; no __syncthreads needed).
    lsum_a += __shfl_xor(lsum_a, 32);
    lsum_b += __shfl_xor(lsum_b, 32);
    float* Ltab = &Ltab_s[w][0];
    if (hi == 0) {
        Ltab[ln] = lsum_a;
        Ltab[32 + ln] = lsum_b;
    }
    F16* Elds = &Epi[w][0];                     // [32 q][36]
    const int q = ln;
#pragma unroll
    for (int set = 0; set < 2; ++set) {
        const f32x16 oacc = set ? oaccb : oacca;
#pragma unroll
        for (int r = 0; r < 16; ++r) {
            const int qr = (r & 3) + 8 * (r >> 2) + 4 * hi;
            const float invr = __builtin_amdgcn_rcpf(Ltab[set * 32 + qr]);
            Elds[qr * 36 + ln] = (F16)(oacc[r] * invr);
        }
        // O_t: [b][nb][t=h][kg][row][8]
        const int g = qpair * 256 + w * 64 + set * 32;   // block-local q base
        const int nb = s * 8 + (g >> 7);
        const int row0 = g & 127;
        F16* Ob = O + (size_t)b * 1048576 + nb * 32768 + h * 4096;
#pragma unroll
        for (int st = 0; st < 2; ++st) {
            const int kg = hi + 2 * st;
            const f16x8 ov = *(const f16x8*)&Elds[q * 36 + kg * 8];
            *(f16x8*)&Ob[kg * 1024 + (row0 + q) * 8] = ov;
        }
    }
}

// ---------------------------------------------------------------------------
// GEMM2 (unchanged): tiled linear staging for BOTH operands.
// ---------------------------------------------------------------------------
__global__ __launch_bounds__(256) void gemm2_kernel(
    const F16* __restrict__ A,      // We_t tiled
    const F16* __restrict__ B,      // O_t tiled
    const float* __restrict__ bias, // be [512]
    float* __restrict__ Y)          // [B][512][4096]
{
    const int b  = blockIdx.z;
    const int jb = blockIdx.y;               // 0..3
    const int j0 = jb * 128;
    const int nb = blockIdx.x;               // 0..31
    const int n0 = nb * 128;
    const int tid = threadIdx.x;
    const int w = tid >> 6, l = tid & 63;
    const int wr = w >> 1, wc = w & 1;
    const int cl = l & 15, rg = l >> 4;

    __shared__ __align__(16) F16 Ash[2][4096];
    __shared__ __align__(16) F16 Bsh[2][4096];

    f32x4 acc[4][4];
#pragma unroll
    for (int i = 0; i < 4; ++i)
#pragma unroll
        for (int j = 0; j < 4; ++j) acc[i][j] = (f32x4){0.f, 0.f, 0.f, 0.f};

    const int frag_off = rg * 1024 + cl * 8;
    const F16* Abase = A + jb * 32768 + tid * 8;
    const F16* Bbase = B + (size_t)b * 1048576 + nb * 32768 + tid * 8;

#define G2_STAGE(bu, t)                                                        \
    do {                                                                       \
        __builtin_amdgcn_global_load_lds(                                      \
            (const __attribute__((address_space(1))) void*)(Abase + (t) * 4096),\
            (__attribute__((address_space(3))) void*)&Ash[bu][tid * 8],        \
            16, 0, 0);                                                         \
        __builtin_amdgcn_global_load_lds(                                      \
            (const __attribute__((address_space(1))) void*)(Abase + (t) * 4096 \
                + 2048),                                                       \
            (__attribute__((address_space(3))) void*)&Ash[bu][2048 + tid * 8], \
            16, 0, 0);                                                         \
        __builtin_amdgcn_global_load_lds(                                      \
            (const __attribute__((address_space(1))) void*)(Bbase + (t) * 4096),\
            (__attribute__((address_space(3))) void*)&Bsh[bu][tid * 8],        \
            16, 0, 0);                                                         \
        __builtin_amdgcn_global_load_lds(                                      \
            (const __attribute__((address_space(1))) void*)(Bbase + (t) * 4096 \
                + 2048),                                                       \
            (__attribute__((address_space(3))) void*)&Bsh[bu][2048 + tid * 8], \
            16, 0, 0);                                                         \
    } while (0)

    G2_STAGE(0, 0);
    __syncthreads();

    for (int t = 0; t < 8; ++t) {
        const int cur = t & 1;
        if (t < 7) G2_STAGE(cur ^ 1, t + 1);

        f16x8 af[4], bfr[4];
#pragma unroll
        for (int f = 0; f < 4; ++f) {
            af[f]  = *(const f16x8*)&Ash[cur][frag_off + (wr * 64 + f * 16) * 8];
            bfr[f] = *(const f16x8*)&Bsh[cur][frag_off + (wc * 64 + f * 16) * 8];
        }
#pragma unroll
        for (int i = 0; i < 4; ++i)
#pragma unroll
            for (int j = 0; j < 4; ++j)
                acc[i][j] = __builtin_amdgcn_mfma_f32_16x16x32_f16(
                    af[i], bfr[j], acc[i][j], 0, 0, 0);
        __syncthreads();
    }
#undef G2_STAGE

#pragma unroll
    for (int i = 0; i < 4; ++i) {
        const int jj = j0 + wr * 64 + i * 16 + rg * 4;
#pragma unroll
        for (int j = 0; j < 4; ++j) {
            const int nn = n0 + wc * 64 + j * 16 + cl;
#pragma unroll
            for (int r = 0; r < 4; ++r)
                Y[((size_t)b * CIN + jj + r) * NTOK + nn] =
                    acc[i][j][r] + bias[jj + r];
        }
    }
}

// ---------------------------------------------------------------------------
// Workspace: Wc_t 786KB | bcomb 4KB | We_t 256KB | Qb 16.8MB | K_t 16.8MB |
// V_t 16.8MB | xt_t 33.5MB (O_t 16.8MB aliases xt_t after GEMM1). ~84.9 MB.
// ---------------------------------------------------------------------------
extern "C" void kernel_launch(void* const* d_in, const int* in_sizes, int n_in,
                              void* d_out, int out_size, void* d_ws, size_t ws_size,
                              hipStream_t stream)
{
    const float* x    = (const float*)d_in[0];
    const float* Wr   = (const float*)d_in[1];
    const float* br   = (const float*)d_in[2];
    const float* Wqkv = (const float*)d_in[3];
    const float* We   = (const float*)d_in[4];
    const float* be   = (const float*)d_in[5];
    float* out = (float*)d_out;

    char* ws = (char*)d_ws;
    F16*   Wc    = (F16*)ws;      ws += 786432;
    float* bcomb = (float*)ws;    ws += 4096;
    F16*   We_t  = (F16*)ws;      ws += 262144;
    F16*   Qb    = (F16*)ws;      ws += (size_t)BATCH * NTOK * 256 * 2;
    F16*   Kt    = (F16*)ws;      ws += (size_t)BATCH * NH * 4 * 32768 * 2;
    F16*   Vt    = (F16*)ws;      ws += (size_t)BATCH * NH * 4 * 32768 * 2;
    F16*   xt    = (F16*)ws;      // 33.5 MB (tiled)
    F16*   O_t   = (F16*)ws;      // aliases xt (16.8 MB), live after GEMM1

    fuse_weights_kernel<<<J3 / 2, 256, 0, stream>>>(Wr, br, Wqkv, Wc, bcomb);
    convert_we_kernel<<<CIN * CH / 256, 256, 0, stream>>>(We, We_t);
    transpose_convert_kernel<<<dim3(NTOK / 256, CIN / 8, BATCH), 256, 0, stream>>>(x, xt);
    gemm1_kernel<<<dim3(NTOK / 128, J3 / 256, BATCH), 512, 0, stream>>>(
        Wc, xt, bcomb, Qb, Kt, Vt);
    attn_mfma_kernel<<<1024, 256, 0, stream>>>(Qb, Kt, Vt, O_t);
    gemm2_kernel<<<dim3(NTOK / 128, CIN / 128, BATCH), 256, 0, stream>>>(
        We_t, O_t, be, out);
}

// Round 20
// 157.417 us; speedup vs baseline: 2.2536x; 2.2536x over previous
//
#include <hip/hip_runtime.h>
#include <hip/hip_bf16.h>

// Problem constants (B=8, C=512, N=4096, heads=8, splits=4)
#define BATCH 8
#define CIN   512
#define NTOK  4096
#define CH    256      // C2 = C/2
#define J3    768      // 3*C2
#define NH    8        // heads
#define DH    32       // head dim
#define NCH   1024     // tokens per chunk (N / SPLITS)

typedef _Float16 F16;
typedef _Float16 f16x8 __attribute__((ext_vector_type(8)));
typedef _Float16 f16x4 __attribute__((ext_vector_type(4)));
typedef _Float16 f16x2 __attribute__((ext_vector_type(2)));
typedef float    f32x4  __attribute__((ext_vector_type(4)));
typedef float    f32x16 __attribute__((ext_vector_type(16)));

// scale * log2(e) = (1/sqrt(32)) * 1.4426950408889634
#define QSCALE 0.25503483f

// Tiled layouts (16B-linear staging everywhere):
//   Wc_t [jb(3)][t(16)][kg(4)][row(256)][8]
//   xt_t [b][nb(32)][t(16)][kg(4)][row(128)][8]
//   We_t [jb(4)][t(8)][kg(4)][row(128)][8]
//   O_t  [b][nb(32)][t(8)][kg(4)][row(128)][8]
//   Qb   [b][n][256]                      (token-major, q prescaled)
//   K_t  [b][h][s][t(16)][kg(4)][nk(64)][8]   (fragment-coalesced)
//   V_t  [b][h][s][t(16)][vg(8)][d(32)][8]    (fragment-coalesced)

// ---------------------------------------------------------------------------
// Kernel 0 (2 j per block, 384 blocks). Writes tiled Wc_t.
// ---------------------------------------------------------------------------
__global__ __launch_bounds__(256) void fuse_weights_kernel(
    const float* __restrict__ Wr, const float* __restrict__ br,
    const float* __restrict__ Wqkv,
    F16* __restrict__ Wc_t, float* __restrict__ bcomb)
{
    const int j0 = blockIdx.x * 2;
    const int tid = threadIdx.x;
    float a00 = 0.f, a01 = 0.f, a10 = 0.f, a11 = 0.f;
    for (int c2 = 0; c2 < CH; ++c2) {
        const float w0 = Wr[c2 * CIN + tid];
        const float w1 = Wr[c2 * CIN + tid + 256];
        const float q0 = Wqkv[c2 * J3 + j0];        // uniform -> s_load
        const float q1 = Wqkv[c2 * J3 + j0 + 1];
        a00 = fmaf(w0, q0, a00);
        a01 = fmaf(w1, q0, a01);
        a10 = fmaf(w0, q1, a10);
        a11 = fmaf(w1, q1, a11);
    }
    const int c0 = tid, c1 = tid + 256;
    const int off0 = (c0 >> 5) * 8192 + ((c0 >> 3) & 3) * 2048 + (c0 & 7);
    const int off1 = (c1 >> 5) * 8192 + ((c1 >> 3) & 3) * 2048 + (c1 & 7);
#pragma unroll
    for (int jj = 0; jj < 2; ++jj) {
        const int j = j0 + jj;
        const float qs = (j < 256) ? QSCALE : 1.0f;
        const int jb = j >> 8, row = j & 255;
        const float v0 = jj ? a10 : a00, v1 = jj ? a11 : a01;
        Wc_t[jb * 131072 + off0 + row * 8] = (F16)(v0 * qs);
        Wc_t[jb * 131072 + off1 + row * 8] = (F16)(v1 * qs);
    }
    if (tid < 2) {
        const int j = j0 + tid;
        const float qs = (j < 256) ? QSCALE : 1.0f;
        float s = 0.f;
        for (int c2 = 0; c2 < CH; ++c2) s = fmaf(Wqkv[c2 * J3 + j], br[c2], s);
        bcomb[j] = s * qs;
    }
}

// ---------------------------------------------------------------------------
// convert We [512][256] f32 -> We_t tiled f16
// ---------------------------------------------------------------------------
__global__ __launch_bounds__(256) void convert_we_kernel(
    const float* __restrict__ We, F16* __restrict__ We_t)
{
    const int i = blockIdx.x * 256 + threadIdx.x;
    const int j = i >> 8, c2 = i & 255;
    We_t[(j >> 7) * 32768 + (c2 >> 5) * 4096 + ((c2 >> 3) & 3) * 1024 +
         (j & 127) * 8 + (c2 & 7)] = (F16)We[i];
}

// ---------------------------------------------------------------------------
// transpose-convert x [B][512][4096] f32 -> xt_t tiled f16
// ---------------------------------------------------------------------------
__global__ __launch_bounds__(256) void transpose_convert_kernel(
    const float* __restrict__ x, F16* __restrict__ xt_t)
{
    const int b = blockIdx.z;
    const int c0 = blockIdx.y * 8;
    const int n = blockIdx.x * 256 + threadIdx.x;

    const float* xb = x + ((size_t)b * CIN + c0) * NTOK + n;
    f16x8 v;
#pragma unroll
    for (int i = 0; i < 8; ++i)
        v[i] = (F16)xb[(size_t)i * NTOK];

    const int nb = n >> 7, row = n & 127;
    const int t = c0 >> 5, kg = (c0 >> 3) & 3;
    *(f16x8*)&xt_t[(size_t)b * 2097152 + nb * 65536 + t * 4096 + kg * 1024 +
                   row * 8] = v;
}

// ---------------------------------------------------------------------------
// GEMM1 (unchanged): 256j x 128n tile, 512 thr, tiled linear staging.
// Epilogues write attn-native layouts: jb=0 -> Qb, jb=1 -> K_t, jb=2 -> V_t.
// ---------------------------------------------------------------------------
__global__ __launch_bounds__(512, 4) void gemm1_kernel(
    const F16* __restrict__ A,      // Wc_t tiled
    const F16* __restrict__ B,      // xt_t tiled
    const float* __restrict__ bias, // bcomb [768]
    F16* __restrict__ Qb,           // [B][4096][256]
    F16* __restrict__ Kt,           // [B][8][4][16][4][64][8]
    F16* __restrict__ Vt)           // [B][8][4][16][8][32][8]
{
    const int b  = blockIdx.z;
    const int jb = blockIdx.y;                // 0..2
    const int j0 = jb * 256;
    const int nb = blockIdx.x;                // 0..31
    const int n0 = nb * 128;
    const int tid = threadIdx.x;
    const int w = tid >> 6, l = tid & 63;
    const int wr = w >> 1;          // 0..3 : j-wave
    const int wc = w & 1;           // 0..1 : n-wave
    const int cl = l & 15, rg = l >> 4;

    __shared__ __align__(16) char smem[49152];
    F16* Ash0 = (F16*)smem;
    F16* Ash1 = (F16*)(smem + 16384);
    F16* Bsh0 = (F16*)(smem + 32768);
    F16* Bsh1 = (F16*)(smem + 40960);
    F16* Esh  = (F16*)smem;

    f32x4 acc[4][4];
#pragma unroll
    for (int i = 0; i < 4; ++i)
#pragma unroll
        for (int j = 0; j < 4; ++j) acc[i][j] = (f32x4){0.f, 0.f, 0.f, 0.f};

    const F16* Abase = A + jb * 131072 + tid * 8;
    const F16* Bbase = B + (size_t)b * 2097152 + nb * 65536 + tid * 8;

#define G1_STAGE(Adst, Bdst, t)                                                \
    do {                                                                       \
        __builtin_amdgcn_global_load_lds(                                      \
            (const __attribute__((address_space(1))) void*)(Abase + (t) * 8192),\
            (__attribute__((address_space(3))) void*)&Adst[tid * 8], 16, 0, 0);\
        __builtin_amdgcn_global_load_lds(                                      \
            (const __attribute__((address_space(1))) void*)(Abase + (t) * 8192 \
                + 4096),                                                       \
            (__attribute__((address_space(3))) void*)&Adst[4096 + tid * 8],    \
            16, 0, 0);                                                         \
        __builtin_amdgcn_global_load_lds(                                      \
            (const __attribute__((address_space(1))) void*)(Bbase + (t) * 4096),\
            (__attribute__((address_space(3))) void*)&Bdst[tid * 8], 16, 0, 0);\
    } while (0)

    G1_STAGE(Ash0, Bsh0, 0);
    __syncthreads();

    for (int t = 0; t < 16; ++t) {
        F16* Ac = (t & 1) ? Ash1 : Ash0;
        F16* Bc = (t & 1) ? Bsh1 : Bsh0;
        if (t < 15) {
            F16* An = (t & 1) ? Ash0 : Ash1;
            F16* Bn = (t & 1) ? Bsh0 : Bsh1;
            G1_STAGE(An, Bn, t + 1);
        }
        f16x8 bf[4];
#pragma unroll
        for (int j = 0; j < 4; ++j)
            bf[j] = *(const f16x8*)&Bc[rg * 1024 + (wc * 64 + j * 16 + cl) * 8];
#pragma unroll
        for (int i = 0; i < 4; ++i) {
            const f16x8 af =
                *(const f16x8*)&Ac[rg * 2048 + (wr * 64 + i * 16 + cl) * 8];
#pragma unroll
            for (int j = 0; j < 4; ++j)
                acc[i][j] = __builtin_amdgcn_mfma_f32_16x16x32_f16(
                    af, bf[j], acc[i][j], 0, 0, 0);
        }
        __syncthreads();
    }
#undef G1_STAGE

    const int sidx = n0 >> 10;          // chunk (constant per block)
    const int tb   = (n0 >> 6) & 15;    // tile base within chunk

    if (jb < 2) {
        // ---- Q/K retile: Esh [nl 32][jl 256+8=264]
        const size_t bN = (size_t)b * NTOK;
#pragma unroll
        for (int c = 0; c < 4; ++c) {
            if (c) __syncthreads();
            if (wc == (c >> 1)) {
#pragma unroll
                for (int i = 0; i < 4; ++i) {
#pragma unroll
                    for (int jj = 0; jj < 2; ++jj) {
                        const int jn = (c & 1) * 2 + jj;
                        const int nl = jj * 16 + cl;
                        const int jl = wr * 64 + i * 16 + rg * 4;
                        const int jg = j0 + jl;
                        f16x4 v;
#pragma unroll
                        for (int r = 0; r < 4; ++r)
                            v[r] = (F16)(acc[i][jn][r] + bias[jg + r]);
                        *(f16x4*)&Esh[nl * 264 + jl] = v;
                    }
                }
            }
            __syncthreads();
            if (jb == 0) {
                // Qb token-major: rows of 256 F16
                const int rr = tid >> 4, ss = tid & 15;
                const f16x8 ov0 = *(const f16x8*)&Esh[rr * 264 + ss * 16];
                const f16x8 ov1 = *(const f16x8*)&Esh[rr * 264 + ss * 16 + 8];
                F16* dst = &Qb[(bN + n0 + c * 32 + rr) * 256 + ss * 16];
                *(f16x8*)dst = ov0;
                *(f16x8*)(dst + 8) = ov1;
            } else {
                // K_t: unit (hh, kg, nl) of 8 F16; nk = (c&1)*32+nl
                const int tloc = (tb + (c >> 1)) & 15;
#pragma unroll
                for (int p = 0; p < 2; ++p) {
                    const int uid = tid + p * 512;
                    const int nl = uid & 31, kg = (uid >> 5) & 3,
                              hh = uid >> 7;
                    const f16x8 ov =
                        *(const f16x8*)&Esh[nl * 264 + hh * 32 + kg * 8];
                    const int nk = (c & 1) * 32 + nl;
                    *(f16x8*)&Kt[(((size_t)b * NH + hh) * 4 + sidx) * 32768 +
                                 tloc * 2048 + kg * 512 + nk * 8] = ov;
                }
            }
        }
    } else {
        // ---- V retile (transposed): Esh [jl 64][nn 136]
#pragma unroll
        for (int c = 0; c < 4; ++c) {
            if (c) __syncthreads();
            if (wr == c) {
#pragma unroll
                for (int i = 0; i < 4; ++i) {
                    const int jg = j0 + c * 64 + i * 16 + rg * 4;
#pragma unroll
                    for (int jn = 0; jn < 4; ++jn) {
                        const int nl = wc * 64 + jn * 16 + cl;
#pragma unroll
                        for (int r = 0; r < 4; ++r)
                            Esh[(i * 16 + rg * 4 + r) * 136 + nl] =
                                (F16)(acc[i][jn][r] + bias[jg + r]);
                    }
                }
            }
            __syncthreads();
            // V_t: unit (hl, ttv, vg, d) of 8 F16 (e = nk&7 contiguous)
#pragma unroll
            for (int p = 0; p < 2; ++p) {
                const int uid = tid + p * 512;
                const int d = uid & 31, vg = (uid >> 5) & 7,
                          ttv = (uid >> 8) & 1, hl = uid >> 9;
                const int hh = c * 2 + hl;
                const int tloc = (tb + ttv) & 15;
                const f16x8 ov =
                    *(const f16x8*)&Esh[(hl * 32 + d) * 136 + ttv * 64 + vg * 8];
                *(f16x8*)&Vt[(((size_t)b * NH + hh) * 4 + sidx) * 32768 +
                             tloc * 2048 + vg * 256 + d * 8] = ov;
            }
        }
    }
}

// ---------------------------------------------------------------------------
// MFMA attention R20: zero-LDS-staging / zero-barrier (R19 structure) with
// the register budget FIXED: __launch_bounds__(256, 4) -> 128 VGPR cap, no
// accumulator spill (R19's (256,8) forced a 64-VGPR cap and spilled 575MB
// to scratch). Fragments load directly from fragment-coalesced K_t/V_t.
// ---------------------------------------------------------------------------
__global__ __launch_bounds__(256, 4) void attn_mfma_kernel(
    const F16* __restrict__ Qb,   // [B][4096][256] (q prescaled)
    const F16* __restrict__ Kt,   // [B][8][4][16][4][64][8]
    const F16* __restrict__ Vt,   // [B][8][4][16][8][32][8]
    F16* __restrict__ O)          // O_t tiled [b][nb][t][kg][row][8]
{
    const int bid = blockIdx.x;
    const int xcd = bid & 7, tt = bid >> 3;
    const int qpair = tt & 3;               // 0..3 (pair of 128-row blocks)
    const int pr = xcd * 32 + (tt >> 2);    // 0..255
    const int s = pr & 3, bh = pr >> 2;
    const int b = bh >> 3, h = bh & 7;
    const int tid = threadIdx.x;
    const int w = tid >> 6, l = tid & 63;
    const int ln = l & 31;          // q-col (QK) / d-col (PV)
    const int hi = l >> 5;

    __shared__ __align__(16) F16 Epi[4][1152];    // per-wave [32 q][36]
    __shared__ __align__(16) float Ltab_s[4][64]; // per-wave lsum table

    const size_t bN = (size_t)b * NTOK + (size_t)s * NCH;
    const int q0 = qpair * 256 + w * 64;    // wave's 64 q-rows

    // Q B-frags for both sets (d 0-15 / 16-31), prescaled in GEMM1
    const F16* Qpa = Qb + (bN + q0 + ln) * 256 + h * DH + hi * 8;
    const F16* Qpb = Qpa + 32 * 256;
    const f16x8 qfa0 = *(const f16x8*)Qpa;
    const f16x8 qfa1 = *(const f16x8*)(Qpa + 16);
    const f16x8 qfb0 = *(const f16x8*)Qpb;
    const f16x8 qfb1 = *(const f16x8*)(Qpb + 16);

    // direct fragment bases (tiled, fragment-coalesced)
    const F16* Kb = Kt + (((size_t)b * NH + h) * 4 + s) * 32768;
    const F16* Vb = Vt + (((size_t)b * NH + h) * 4 + s) * 32768;

    f32x16 oacca = (f32x16)(0.0f);
    f32x16 oaccb = (f32x16)(0.0f);
    float lsum_a = 0.f, lsum_b = 0.f;

    for (int t = 0; t < 16; ++t) {
#pragma unroll
        for (int u = 0; u < 2; ++u) {
            // K A-frags: kf0 at kg=hi, kf1 at kg=2+hi; row nk = u*32+ln
            const f16x8 kf0 =
                *(const f16x8*)&Kb[t * 2048 + hi * 512 + (u * 32 + ln) * 8];
            const f16x8 kf1 =
                *(const f16x8*)&Kb[t * 2048 + (2 + hi) * 512 + (u * 32 + ln) * 8];

            // ---- set a: QK -> exp2 -> pkrtz -> lsum tree
            f32x16 sacc = (f32x16)(0.0f);
            __builtin_amdgcn_s_setprio(1);
            sacc = __builtin_amdgcn_mfma_f32_32x32x16_f16(kf0, qfa0, sacc, 0, 0, 0);
            sacc = __builtin_amdgcn_mfma_f32_32x32x16_f16(kf1, qfa1, sacc, 0, 0, 0);
            __builtin_amdgcn_s_setprio(0);
            union { f16x8 v; f16x2 h[4]; } pa0, pa1, pb0, pb1;
#pragma unroll
            for (int e = 0; e < 4; ++e) {
                pa0.h[e] = __builtin_bit_cast(f16x2, __builtin_amdgcn_cvt_pkrtz(
                    __builtin_amdgcn_exp2f(sacc[2 * e]),
                    __builtin_amdgcn_exp2f(sacc[2 * e + 1])));
                pa1.h[e] = __builtin_bit_cast(f16x2, __builtin_amdgcn_cvt_pkrtz(
                    __builtin_amdgcn_exp2f(sacc[8 + 2 * e]),
                    __builtin_amdgcn_exp2f(sacc[8 + 2 * e + 1])));
            }
            {
                const f16x2 t01 = pa0.h[0] + pa0.h[1] + pa1.h[0] + pa1.h[1];
                const f16x2 t23 = pa0.h[2] + pa0.h[3] + pa1.h[2] + pa1.h[3];
                const f16x2 ts = t01 + t23;
                lsum_a += (float)ts[0] + (float)ts[1];
            }

            // ---- set b: QK -> exp2 -> pkrtz -> lsum tree
            f32x16 sb = (f32x16)(0.0f);
            __builtin_amdgcn_s_setprio(1);
            sb = __builtin_amdgcn_mfma_f32_32x32x16_f16(kf0, qfb0, sb, 0, 0, 0);
            sb = __builtin_amdgcn_mfma_f32_32x32x16_f16(kf1, qfb1, sb, 0, 0, 0);
            __builtin_amdgcn_s_setprio(0);
#pragma unroll
            for (int e = 0; e < 4; ++e) {
                pb0.h[e] = __builtin_bit_cast(f16x2, __builtin_amdgcn_cvt_pkrtz(
                    __builtin_amdgcn_exp2f(sb[2 * e]),
                    __builtin_amdgcn_exp2f(sb[2 * e + 1])));
                pb1.h[e] = __builtin_bit_cast(f16x2, __builtin_amdgcn_cvt_pkrtz(
                    __builtin_amdgcn_exp2f(sb[8 + 2 * e]),
                    __builtin_amdgcn_exp2f(sb[8 + 2 * e + 1])));
            }
            {
                const f16x2 t01 = pb0.h[0] + pb0.h[1] + pb1.h[0] + pb1.h[1];
                const f16x2 t23 = pb0.h[2] + pb0.h[3] + pb1.h[2] + pb1.h[3];
                const f16x2 ts = t01 + t23;
                lsum_b += (float)ts[0] + (float)ts[1];
            }

            // V B-frags direct from V_t (sigma order): vg = u*4 + {0,1,2,3},
            // each lane reads 8B at [vg][d=ln][e0=4*hi].
            const int vb0 = t * 2048 + (u * 4) * 256 + ln * 8 + 4 * hi;
            const f16x4 v00 = *(const f16x4*)&Vb[vb0];
            const f16x4 v01 = *(const f16x4*)&Vb[vb0 + 256];
            const f16x4 v10 = *(const f16x4*)&Vb[vb0 + 512];
            const f16x4 v11 = *(const f16x4*)&Vb[vb0 + 768];
            const f16x8 vf0 = __builtin_shufflevector(v00, v01, 0, 1, 2, 3, 4, 5, 6, 7);
            const f16x8 vf1 = __builtin_shufflevector(v10, v11, 0, 1, 2, 3, 4, 5, 6, 7);

            __builtin_amdgcn_s_setprio(1);
            oacca = __builtin_amdgcn_mfma_f32_32x32x16_f16(pa0.v, vf0, oacca, 0, 0, 0);
            oacca = __builtin_amdgcn_mfma_f32_32x32x16_f16(pa1.v, vf1, oacca, 0, 0, 0);
            oaccb = __builtin_amdgcn_mfma_f32_32x32x16_f16(pb0.v, vf0, oaccb, 0, 0, 0);
            oaccb = __builtin_amdgcn_mfma_f32_32x32x16_f16(pb1.v, vf1, oaccb, 0, 0, 0);
            __builtin_amdgcn_s_setprio(0);
        }
    }

    // ---- epilogue (per-wave private LDS; no __syncthreads needed).
    lsum_a += __shfl_xor(lsum_a, 32);
    lsum_b += __shfl_xor(lsum_b, 32);
    float* Ltab = &Ltab_s[w][0];
    if (hi == 0) {
        Ltab[ln] = lsum_a;
        Ltab[32 + ln] = lsum_b;
    }
    F16* Elds = &Epi[w][0];                     // [32 q][36]
    const int q = ln;
#pragma unroll
    for (int set = 0; set < 2; ++set) {
        const f32x16 oacc = set ? oaccb : oacca;
#pragma unroll
        for (int r = 0; r < 16; ++r) {
            const int qr = (r & 3) + 8 * (r >> 2) + 4 * hi;
            const float invr = __builtin_amdgcn_rcpf(Ltab[set * 32 + qr]);
            Elds[qr * 36 + ln] = (F16)(oacc[r] * invr);
        }
        // O_t: [b][nb][t=h][kg][row][8]
        const int g = qpair * 256 + w * 64 + set * 32;   // block-local q base
        const int nb = s * 8 + (g >> 7);
        const int row0 = g & 127;
        F16* Ob = O + (size_t)b * 1048576 + nb * 32768 + h * 4096;
#pragma unroll
        for (int st = 0; st < 2; ++st) {
            const int kg = hi + 2 * st;
            const f16x8 ov = *(const f16x8*)&Elds[q * 36 + kg * 8];
            *(f16x8*)&Ob[kg * 1024 + (row0 + q) * 8] = ov;
        }
    }
}

// ---------------------------------------------------------------------------
// GEMM2 (unchanged): tiled linear staging for BOTH operands.
// ---------------------------------------------------------------------------
__global__ __launch_bounds__(256) void gemm2_kernel(
    const F16* __restrict__ A,      // We_t tiled
    const F16* __restrict__ B,      // O_t tiled
    const float* __restrict__ bias, // be [512]
    float* __restrict__ Y)          // [B][512][4096]
{
    const int b  = blockIdx.z;
    const int jb = blockIdx.y;               // 0..3
    const int j0 = jb * 128;
    const int nb = blockIdx.x;               // 0..31
    const int n0 = nb * 128;
    const int tid = threadIdx.x;
    const int w = tid >> 6, l = tid & 63;
    const int wr = w >> 1, wc = w & 1;
    const int cl = l & 15, rg = l >> 4;

    __shared__ __align__(16) F16 Ash[2][4096];
    __shared__ __align__(16) F16 Bsh[2][4096];

    f32x4 acc[4][4];
#pragma unroll
    for (int i = 0; i < 4; ++i)
#pragma unroll
        for (int j = 0; j < 4; ++j) acc[i][j] = (f32x4){0.f, 0.f, 0.f, 0.f};

    const int frag_off = rg * 1024 + cl * 8;
    const F16* Abase = A + jb * 32768 + tid * 8;
    const F16* Bbase = B + (size_t)b * 1048576 + nb * 32768 + tid * 8;

#define G2_STAGE(bu, t)                                                        \
    do {                                                                       \
        __builtin_amdgcn_global_load_lds(                                      \
            (const __attribute__((address_space(1))) void*)(Abase + (t) * 4096),\
            (__attribute__((address_space(3))) void*)&Ash[bu][tid * 8],        \
            16, 0, 0);                                                         \
        __builtin_amdgcn_global_load_lds(                                      \
            (const __attribute__((address_space(1))) void*)(Abase + (t) * 4096 \
                + 2048),                                                       \
            (__attribute__((address_space(3))) void*)&Ash[bu][2048 + tid * 8], \
            16, 0, 0);                                                         \
        __builtin_amdgcn_global_load_lds(                                      \
            (const __attribute__((address_space(1))) void*)(Bbase + (t) * 4096),\
            (__attribute__((address_space(3))) void*)&Bsh[bu][tid * 8],        \
            16, 0, 0);                                                         \
        __builtin_amdgcn_global_load_lds(                                      \
            (const __attribute__((address_space(1))) void*)(Bbase + (t) * 4096 \
                + 2048),                                                       \
            (__attribute__((address_space(3))) void*)&Bsh[bu][2048 + tid * 8], \
            16, 0, 0);                                                         \
    } while (0)

    G2_STAGE(0, 0);
    __syncthreads();

    for (int t = 0; t < 8; ++t) {
        const int cur = t & 1;
        if (t < 7) G2_STAGE(cur ^ 1, t + 1);

        f16x8 af[4], bfr[4];
#pragma unroll
        for (int f = 0; f < 4; ++f) {
            af[f]  = *(const f16x8*)&Ash[cur][frag_off + (wr * 64 + f * 16) * 8];
            bfr[f] = *(const f16x8*)&Bsh[cur][frag_off + (wc * 64 + f * 16) * 8];
        }
#pragma unroll
        for (int i = 0; i < 4; ++i)
#pragma unroll
            for (int j = 0; j < 4; ++j)
                acc[i][j] = __builtin_amdgcn_mfma_f32_16x16x32_f16(
                    af[i], bfr[j], acc[i][j], 0, 0, 0);
        __syncthreads();
    }
#undef G2_STAGE

#pragma unroll
    for (int i = 0; i < 4; ++i) {
        const int jj = j0 + wr * 64 + i * 16 + rg * 4;
#pragma unroll
        for (int j = 0; j < 4; ++j) {
            const int nn = n0 + wc * 64 + j * 16 + cl;
#pragma unroll
            for (int r = 0; r < 4; ++r)
                Y[((size_t)b * CIN + jj + r) * NTOK + nn] =
                    acc[i][j][r] + bias[jj + r];
        }
    }
}

// ---------------------------------------------------------------------------
// Workspace: Wc_t 786KB | bcomb 4KB | We_t 256KB | Qb 16.8MB | K_t 16.8MB |
// V_t 16.8MB | xt_t 33.5MB (O_t 16.8MB aliases xt_t after GEMM1). ~84.9 MB.
// ---------------------------------------------------------------------------
extern "C" void kernel_launch(void* const* d_in, const int* in_sizes, int n_in,
                              void* d_out, int out_size, void* d_ws, size_t ws_size,
                              hipStream_t stream)
{
    const float* x    = (const float*)d_in[0];
    const float* Wr   = (const float*)d_in[1];
    const float* br   = (const float*)d_in[2];
    const float* Wqkv = (const float*)d_in[3];
    const float* We   = (const float*)d_in[4];
    const float* be   = (const float*)d_in[5];
    float* out = (float*)d_out;

    char* ws = (char*)d_ws;
    F16*   Wc    = (F16*)ws;      ws += 786432;
    float* bcomb = (float*)ws;    ws += 4096;
    F16*   We_t  = (F16*)ws;      ws += 262144;
    F16*   Qb    = (F16*)ws;      ws += (size_t)BATCH * NTOK * 256 * 2;
    F16*   Kt    = (F16*)ws;      ws += (size_t)BATCH * NH * 4 * 32768 * 2;
    F16*   Vt    = (F16*)ws;      ws += (size_t)BATCH * NH * 4 * 32768 * 2;
    F16*   xt    = (F16*)ws;      // 33.5 MB (tiled)
    F16*   O_t   = (F16*)ws;      // aliases xt (16.8 MB), live after GEMM1

    fuse_weights_kernel<<<J3 / 2, 256, 0, stream>>>(Wr, br, Wqkv, Wc, bcomb);
    convert_we_kernel<<<CIN * CH / 256, 256, 0, stream>>>(We, We_t);
    transpose_convert_kernel<<<dim3(NTOK / 256, CIN / 8, BATCH), 256, 0, stream>>>(x, xt);
    gemm1_kernel<<<dim3(NTOK / 128, J3 / 256, BATCH), 512, 0, stream>>>(
        Wc, xt, bcomb, Qb, Kt, Vt);
    attn_mfma_kernel<<<1024, 256, 0, stream>>>(Qb, Kt, Vt, O_t);
    gemm2_kernel<<<dim3(NTOK / 128, CIN / 128, BATCH), 256, 0, stream>>>(
        We_t, O_t, be, out);
}

// Round 21
// 153.562 us; speedup vs baseline: 2.3102x; 1.0251x over previous
//
#include <hip/hip_runtime.h>
#include <hip/hip_bf16.h>

// Problem constants (B=8, C=512, N=4096, heads=8, splits=4)
#define BATCH 8
#define CIN   512
#define NTOK  4096
#define CH    256      // C2 = C/2
#define J3    768      // 3*C2
#define NH    8        // heads
#define DH    32       // head dim
#define NCH   1024     // tokens per chunk (N / SPLITS)

typedef _Float16 F16;
typedef _Float16 f16x8 __attribute__((ext_vector_type(8)));
typedef _Float16 f16x4 __attribute__((ext_vector_type(4)));
typedef _Float16 f16x2 __attribute__((ext_vector_type(2)));
typedef float    f32x4  __attribute__((ext_vector_type(4)));
typedef float    f32x16 __attribute__((ext_vector_type(16)));

// scale * log2(e) = (1/sqrt(32)) * 1.4426950408889634
#define QSCALE 0.25503483f

// Tiled layouts (16B-linear staging everywhere):
//   Wc_t [jb(3)][t(16)][kg(4)][row(256)][8]
//   xt_t [b][nb(32)][t(16)][kg(4)][row(128)][8]
//   We_t [jb(2)][t(8)][kg(4)][row(256)][8]    (R21: 256-row blocks for gemm2)
//   O_t  [b][nb(32)][t(8)][kg(4)][row(128)][8]
//   Qb   [b][n][256]                      (token-major, q prescaled)
//   K_t  [b][h][s][t(16)][kg(4)][nk(64)][8]   (attn-LDS-tile-ready)
//   V_t  [b][h][s][t(16)][vg(8)][d(32)][8]    (attn-LDS-tile-ready)

// ---------------------------------------------------------------------------
// Kernel 0 (2 j per block, 384 blocks). Writes tiled Wc_t.
// ---------------------------------------------------------------------------
__global__ __launch_bounds__(256) void fuse_weights_kernel(
    const float* __restrict__ Wr, const float* __restrict__ br,
    const float* __restrict__ Wqkv,
    F16* __restrict__ Wc_t, float* __restrict__ bcomb)
{
    const int j0 = blockIdx.x * 2;
    const int tid = threadIdx.x;
    float a00 = 0.f, a01 = 0.f, a10 = 0.f, a11 = 0.f;
    for (int c2 = 0; c2 < CH; ++c2) {
        const float w0 = Wr[c2 * CIN + tid];
        const float w1 = Wr[c2 * CIN + tid + 256];
        const float q0 = Wqkv[c2 * J3 + j0];        // uniform -> s_load
        const float q1 = Wqkv[c2 * J3 + j0 + 1];
        a00 = fmaf(w0, q0, a00);
        a01 = fmaf(w1, q0, a01);
        a10 = fmaf(w0, q1, a10);
        a11 = fmaf(w1, q1, a11);
    }
    const int c0 = tid, c1 = tid + 256;
    const int off0 = (c0 >> 5) * 8192 + ((c0 >> 3) & 3) * 2048 + (c0 & 7);
    const int off1 = (c1 >> 5) * 8192 + ((c1 >> 3) & 3) * 2048 + (c1 & 7);
#pragma unroll
    for (int jj = 0; jj < 2; ++jj) {
        const int j = j0 + jj;
        const float qs = (j < 256) ? QSCALE : 1.0f;
        const int jb = j >> 8, row = j & 255;
        const float v0 = jj ? a10 : a00, v1 = jj ? a11 : a01;
        Wc_t[jb * 131072 + off0 + row * 8] = (F16)(v0 * qs);
        Wc_t[jb * 131072 + off1 + row * 8] = (F16)(v1 * qs);
    }
    if (tid < 2) {
        const int j = j0 + tid;
        const float qs = (j < 256) ? QSCALE : 1.0f;
        float s = 0.f;
        for (int c2 = 0; c2 < CH; ++c2) s = fmaf(Wqkv[c2 * J3 + j], br[c2], s);
        bcomb[j] = s * qs;
    }
}

// ---------------------------------------------------------------------------
// convert We [512][256] f32 -> We_t tiled f16 (R21: 256-row j-blocks)
// ---------------------------------------------------------------------------
__global__ __launch_bounds__(256) void convert_we_kernel(
    const float* __restrict__ We, F16* __restrict__ We_t)
{
    const int i = blockIdx.x * 256 + threadIdx.x;
    const int j = i >> 8, c2 = i & 255;
    We_t[(j >> 8) * 65536 + (c2 >> 5) * 8192 + ((c2 >> 3) & 3) * 2048 +
         (j & 255) * 8 + (c2 & 7)] = (F16)We[i];
}

// ---------------------------------------------------------------------------
// transpose-convert x [B][512][4096] f32 -> xt_t tiled f16
// ---------------------------------------------------------------------------
__global__ __launch_bounds__(256) void transpose_convert_kernel(
    const float* __restrict__ x, F16* __restrict__ xt_t)
{
    const int b = blockIdx.z;
    const int c0 = blockIdx.y * 8;
    const int n = blockIdx.x * 256 + threadIdx.x;

    const float* xb = x + ((size_t)b * CIN + c0) * NTOK + n;
    f16x8 v;
#pragma unroll
    for (int i = 0; i < 8; ++i)
        v[i] = (F16)xb[(size_t)i * NTOK];

    const int nb = n >> 7, row = n & 127;
    const int t = c0 >> 5, kg = (c0 >> 3) & 3;
    *(f16x8*)&xt_t[(size_t)b * 2097152 + nb * 65536 + t * 4096 + kg * 1024 +
                   row * 8] = v;
}

// ---------------------------------------------------------------------------
// GEMM1 (unchanged): 256j x 128n tile, 512 thr, tiled linear staging.
// Epilogues write attn-native layouts: jb=0 -> Qb, jb=1 -> K_t, jb=2 -> V_t.
// ---------------------------------------------------------------------------
__global__ __launch_bounds__(512, 4) void gemm1_kernel(
    const F16* __restrict__ A,      // Wc_t tiled
    const F16* __restrict__ B,      // xt_t tiled
    const float* __restrict__ bias, // bcomb [768]
    F16* __restrict__ Qb,           // [B][4096][256]
    F16* __restrict__ Kt,           // [B][8][4][16][4][64][8]
    F16* __restrict__ Vt)           // [B][8][4][16][8][32][8]
{
    const int b  = blockIdx.z;
    const int jb = blockIdx.y;                // 0..2
    const int j0 = jb * 256;
    const int nb = blockIdx.x;                // 0..31
    const int n0 = nb * 128;
    const int tid = threadIdx.x;
    const int w = tid >> 6, l = tid & 63;
    const int wr = w >> 1;          // 0..3 : j-wave
    const int wc = w & 1;           // 0..1 : n-wave
    const int cl = l & 15, rg = l >> 4;

    __shared__ __align__(16) char smem[49152];
    F16* Ash0 = (F16*)smem;
    F16* Ash1 = (F16*)(smem + 16384);
    F16* Bsh0 = (F16*)(smem + 32768);
    F16* Bsh1 = (F16*)(smem + 40960);
    F16* Esh  = (F16*)smem;

    f32x4 acc[4][4];
#pragma unroll
    for (int i = 0; i < 4; ++i)
#pragma unroll
        for (int j = 0; j < 4; ++j) acc[i][j] = (f32x4){0.f, 0.f, 0.f, 0.f};

    const F16* Abase = A + jb * 131072 + tid * 8;
    const F16* Bbase = B + (size_t)b * 2097152 + nb * 65536 + tid * 8;

#define G1_STAGE(Adst, Bdst, t)                                                \
    do {                                                                       \
        __builtin_amdgcn_global_load_lds(                                      \
            (const __attribute__((address_space(1))) void*)(Abase + (t) * 8192),\
            (__attribute__((address_space(3))) void*)&Adst[tid * 8], 16, 0, 0);\
        __builtin_amdgcn_global_load_lds(                                      \
            (const __attribute__((address_space(1))) void*)(Abase + (t) * 8192 \
                + 4096),                                                       \
            (__attribute__((address_space(3))) void*)&Adst[4096 + tid * 8],    \
            16, 0, 0);                                                         \
        __builtin_amdgcn_global_load_lds(                                      \
            (const __attribute__((address_space(1))) void*)(Bbase + (t) * 4096),\
            (__attribute__((address_space(3))) void*)&Bdst[tid * 8], 16, 0, 0);\
    } while (0)

    G1_STAGE(Ash0, Bsh0, 0);
    __syncthreads();

    for (int t = 0; t < 16; ++t) {
        F16* Ac = (t & 1) ? Ash1 : Ash0;
        F16* Bc = (t & 1) ? Bsh1 : Bsh0;
        if (t < 15) {
            F16* An = (t & 1) ? Ash0 : Ash1;
            F16* Bn = (t & 1) ? Bsh0 : Bsh1;
            G1_STAGE(An, Bn, t + 1);
        }
        f16x8 bf[4];
#pragma unroll
        for (int j = 0; j < 4; ++j)
            bf[j] = *(const f16x8*)&Bc[rg * 1024 + (wc * 64 + j * 16 + cl) * 8];
#pragma unroll
        for (int i = 0; i < 4; ++i) {
            const f16x8 af =
                *(const f16x8*)&Ac[rg * 2048 + (wr * 64 + i * 16 + cl) * 8];
#pragma unroll
            for (int j = 0; j < 4; ++j)
                acc[i][j] = __builtin_amdgcn_mfma_f32_16x16x32_f16(
                    af, bf[j], acc[i][j], 0, 0, 0);
        }
        __syncthreads();
    }
#undef G1_STAGE

    const int sidx = n0 >> 10;          // chunk (constant per block)
    const int tb   = (n0 >> 6) & 15;    // tile base within chunk

    if (jb < 2) {
        // ---- Q/K retile: Esh [nl 32][jl 256+8=264]
        const size_t bN = (size_t)b * NTOK;
#pragma unroll
        for (int c = 0; c < 4; ++c) {
            if (c) __syncthreads();
            if (wc == (c >> 1)) {
#pragma unroll
                for (int i = 0; i < 4; ++i) {
#pragma unroll
                    for (int jj = 0; jj < 2; ++jj) {
                        const int jn = (c & 1) * 2 + jj;
                        const int nl = jj * 16 + cl;
                        const int jl = wr * 64 + i * 16 + rg * 4;
                        const int jg = j0 + jl;
                        f16x4 v;
#pragma unroll
                        for (int r = 0; r < 4; ++r)
                            v[r] = (F16)(acc[i][jn][r] + bias[jg + r]);
                        *(f16x4*)&Esh[nl * 264 + jl] = v;
                    }
                }
            }
            __syncthreads();
            if (jb == 0) {
                // Qb token-major: rows of 256 F16
                const int rr = tid >> 4, ss = tid & 15;
                const f16x8 ov0 = *(const f16x8*)&Esh[rr * 264 + ss * 16];
                const f16x8 ov1 = *(const f16x8*)&Esh[rr * 264 + ss * 16 + 8];
                F16* dst = &Qb[(bN + n0 + c * 32 + rr) * 256 + ss * 16];
                *(f16x8*)dst = ov0;
                *(f16x8*)(dst + 8) = ov1;
            } else {
                // K_t: unit (hh, kg, nl) of 8 F16; nk = (c&1)*32+nl
                const int tloc = (tb + (c >> 1)) & 15;
#pragma unroll
                for (int p = 0; p < 2; ++p) {
                    const int uid = tid + p * 512;
                    const int nl = uid & 31, kg = (uid >> 5) & 3,
                              hh = uid >> 7;
                    const f16x8 ov =
                        *(const f16x8*)&Esh[nl * 264 + hh * 32 + kg * 8];
                    const int nk = (c & 1) * 32 + nl;
                    *(f16x8*)&Kt[(((size_t)b * NH + hh) * 4 + sidx) * 32768 +
                                 tloc * 2048 + kg * 512 + nk * 8] = ov;
                }
            }
        }
    } else {
        // ---- V retile (transposed): Esh [jl 64][nn 136]
#pragma unroll
        for (int c = 0; c < 4; ++c) {
            if (c) __syncthreads();
            if (wr == c) {
#pragma unroll
                for (int i = 0; i < 4; ++i) {
                    const int jg = j0 + c * 64 + i * 16 + rg * 4;
#pragma unroll
                    for (int jn = 0; jn < 4; ++jn) {
                        const int nl = wc * 64 + jn * 16 + cl;
#pragma unroll
                        for (int r = 0; r < 4; ++r)
                            Esh[(i * 16 + rg * 4 + r) * 136 + nl] =
                                (F16)(acc[i][jn][r] + bias[jg + r]);
                    }
                }
            }
            __syncthreads();
            // V_t: unit (hl, ttv, vg, d) of 8 F16 (e = nk&7 contiguous)
#pragma unroll
            for (int p = 0; p < 2; ++p) {
                const int uid = tid + p * 512;
                const int d = uid & 31, vg = (uid >> 5) & 7,
                          ttv = (uid >> 8) & 1, hl = uid >> 9;
                const int hh = c * 2 + hl;
                const int tloc = (tb + ttv) & 15;
                const f16x8 ov =
                    *(const f16x8*)&Esh[(hl * 32 + d) * 136 + ttv * 64 + vg * 8];
                *(f16x8*)&Vt[(((size_t)b * NH + hh) * 4 + sidx) * 32768 +
                             tloc * 2048 + vg * 256 + d * 8] = ov;
            }
        }
    }
}

// ---------------------------------------------------------------------------
// MFMA attention (R18 staged version: 64 q-rows/wave, VALU f16-tree
// denominator + Ltab epilogue -- 56 VGPR, zero spill, 49us proven).
// ---------------------------------------------------------------------------
__global__ __launch_bounds__(256, 4) void attn_mfma_kernel(
    const F16* __restrict__ Qb,   // [B][4096][256] (q prescaled)
    const F16* __restrict__ Kt,   // [B][8][4][16][4][64][8]
    const F16* __restrict__ Vt,   // [B][8][4][16][8][32][8]
    F16* __restrict__ O)          // O_t tiled [b][nb][t][kg][row][8]
{
    const int bid = blockIdx.x;
    const int xcd = bid & 7, tt = bid >> 3;
    const int qpair = tt & 3;               // 0..3 (pair of 128-row blocks)
    const int pr = xcd * 32 + (tt >> 2);    // 0..255
    const int s = pr & 3, bh = pr >> 2;
    const int b = bh >> 3, h = bh & 7;
    const int tid = threadIdx.x;
    const int w = tid >> 6, l = tid & 63;
    const int ln = l & 31;          // q-col (QK) / d-col (PV)
    const int hi = l >> 5;

    __shared__ __align__(16) F16 Klds[2][64 * 40];   // [nk][d], 80B rows
    __shared__ __align__(16) F16 Vlds[2][32 * 68];   // [d][nk], 136B rows

    const size_t bN = (size_t)b * NTOK + (size_t)s * NCH;
    const int q0 = qpair * 256 + w * 64;    // wave's 64 q-rows

    // Q B-frags for both sets (d 0-15 / 16-31), prescaled in GEMM1
    const F16* Qpa = Qb + (bN + q0 + ln) * 256 + h * DH + hi * 8;
    const F16* Qpb = Qpa + 32 * 256;
    const f16x8 qfa0 = *(const f16x8*)Qpa;
    const f16x8 qfa1 = *(const f16x8*)(Qpa + 16);
    const f16x8 qfb0 = *(const f16x8*)Qpb;
    const f16x8 qfb1 = *(const f16x8*)(Qpb + 16);

    // tile-ready staging bases: per tile t, load at base + t*2048 + tid*8
    const F16* Kbase = Kt + (((size_t)b * NH + h) * 4 + s) * 32768 + tid * 8;
    const F16* Vbase = Vt + (((size_t)b * NH + h) * 4 + s) * 32768 + tid * 8;
    const int kw = (tid & 63) * 40 + (tid >> 6) * 8;
    const int vw = (tid & 31) * 68 + (tid >> 5) * 8;

    f16x8 kreg = *(const f16x8*)Kbase;
    f16x8 vreg = *(const f16x8*)Vbase;

    f32x16 oacca = (f32x16)(0.0f);
    f32x16 oaccb = (f32x16)(0.0f);
    float lsum_a = 0.f, lsum_b = 0.f;

    // prologue: fill buffer 0
    *(f16x8*)&Klds[0][kw] = kreg;
    *(f16x4*)&Vlds[0][vw] = __builtin_shufflevector(vreg, vreg, 0, 1, 2, 3);
    *(f16x4*)&Vlds[0][vw + 4] = __builtin_shufflevector(vreg, vreg, 4, 5, 6, 7);

    for (int t = 0; t < 16; ++t) {
        const int cur = t & 1, nxt = cur ^ 1;
        __syncthreads();
        if (t < 15) {
            kreg = *(const f16x8*)(Kbase + (t + 1) * 2048);
            vreg = *(const f16x8*)(Vbase + (t + 1) * 2048);
        }
        const F16* Kb = &Klds[cur][0];
        const F16* Vb = &Vlds[cur][0];
#pragma unroll
        for (int u = 0; u < 2; ++u) {
            const int nkb = u * 32;
            // K A-frags: row nk = ln, k = d = hi*8+e (two d-halves)
            const f16x8 kf0 = *(const f16x8*)&Kb[(nkb + ln) * 40 + hi * 8];
            const f16x8 kf1 = *(const f16x8*)&Kb[(nkb + ln) * 40 + 16 + hi * 8];

            // ---- set a: QK -> exp2 -> pkrtz -> lsum tree
            f32x16 sacc = (f32x16)(0.0f);
            __builtin_amdgcn_s_setprio(1);
            sacc = __builtin_amdgcn_mfma_f32_32x32x16_f16(kf0, qfa0, sacc, 0, 0, 0);
            sacc = __builtin_amdgcn_mfma_f32_32x32x16_f16(kf1, qfa1, sacc, 0, 0, 0);
            __builtin_amdgcn_s_setprio(0);
            union { f16x8 v; f16x2 h[4]; } pa0, pa1, pb0, pb1;
#pragma unroll
            for (int e = 0; e < 4; ++e) {
                pa0.h[e] = __builtin_bit_cast(f16x2, __builtin_amdgcn_cvt_pkrtz(
                    __builtin_amdgcn_exp2f(sacc[2 * e]),
                    __builtin_amdgcn_exp2f(sacc[2 * e + 1])));
                pa1.h[e] = __builtin_bit_cast(f16x2, __builtin_amdgcn_cvt_pkrtz(
                    __builtin_amdgcn_exp2f(sacc[8 + 2 * e]),
                    __builtin_amdgcn_exp2f(sacc[8 + 2 * e + 1])));
            }
            {
                const f16x2 t01 = pa0.h[0] + pa0.h[1] + pa1.h[0] + pa1.h[1];
                const f16x2 t23 = pa0.h[2] + pa0.h[3] + pa1.h[2] + pa1.h[3];
                const f16x2 ts = t01 + t23;
                lsum_a += (float)ts[0] + (float)ts[1];
            }

            // ---- set b: QK -> exp2 -> pkrtz -> lsum tree
            f32x16 sb = (f32x16)(0.0f);
            __builtin_amdgcn_s_setprio(1);
            sb = __builtin_amdgcn_mfma_f32_32x32x16_f16(kf0, qfb0, sb, 0, 0, 0);
            sb = __builtin_amdgcn_mfma_f32_32x32x16_f16(kf1, qfb1, sb, 0, 0, 0);
            __builtin_amdgcn_s_setprio(0);
#pragma unroll
            for (int e = 0; e < 4; ++e) {
                pb0.h[e] = __builtin_bit_cast(f16x2, __builtin_amdgcn_cvt_pkrtz(
                    __builtin_amdgcn_exp2f(sb[2 * e]),
                    __builtin_amdgcn_exp2f(sb[2 * e + 1])));
                pb1.h[e] = __builtin_bit_cast(f16x2, __builtin_amdgcn_cvt_pkrtz(
                    __builtin_amdgcn_exp2f(sb[8 + 2 * e]),
                    __builtin_amdgcn_exp2f(sb[8 + 2 * e + 1])));
            }
            {
                const f16x2 t01 = pb0.h[0] + pb0.h[1] + pb1.h[0] + pb1.h[1];
                const f16x2 t23 = pb0.h[2] + pb0.h[3] + pb1.h[2] + pb1.h[3];
                const f16x2 ts = t01 + t23;
                lsum_b += (float)ts[0] + (float)ts[1];
            }

            // V B-frags in sigma order: nk = (e&3) + 8*((e>>2)&1) + 4*hi (+16)
            const int vbase = ln * 68 + nkb + 4 * hi;
            const f16x4 v00 = *(const f16x4*)&Vb[vbase];
            const f16x4 v01 = *(const f16x4*)&Vb[vbase + 8];
            const f16x4 v10 = *(const f16x4*)&Vb[vbase + 16];
            const f16x4 v11 = *(const f16x4*)&Vb[vbase + 24];
            const f16x8 vf0 = __builtin_shufflevector(v00, v01, 0, 1, 2, 3, 4, 5, 6, 7);
            const f16x8 vf1 = __builtin_shufflevector(v10, v11, 0, 1, 2, 3, 4, 5, 6, 7);

            __builtin_amdgcn_s_setprio(1);
            oacca = __builtin_amdgcn_mfma_f32_32x32x16_f16(pa0.v, vf0, oacca, 0, 0, 0);
            oacca = __builtin_amdgcn_mfma_f32_32x32x16_f16(pa1.v, vf1, oacca, 0, 0, 0);
            oaccb = __builtin_amdgcn_mfma_f32_32x32x16_f16(pb0.v, vf0, oaccb, 0, 0, 0);
            oaccb = __builtin_amdgcn_mfma_f32_32x32x16_f16(pb1.v, vf1, oaccb, 0, 0, 0);
            __builtin_amdgcn_s_setprio(0);
        }
        if (t < 15) {
            *(f16x8*)&Klds[nxt][kw] = kreg;
            *(f16x4*)&Vlds[nxt][vw] =
                __builtin_shufflevector(vreg, vreg, 0, 1, 2, 3);
            *(f16x4*)&Vlds[nxt][vw + 4] =
                __builtin_shufflevector(vreg, vreg, 4, 5, 6, 7);
        }
    }

    // ---- epilogue. lsum lives at lane (ln,hi) for q=ln; combine halves,
    // publish per-wave 64-entry f32 table, then divide + retile + store.
    lsum_a += __shfl_xor(lsum_a, 32);
    lsum_b += __shfl_xor(lsum_b, 32);
    __syncthreads();                         // all waves done with K/V LDS
    float* Ltab = (float*)&Vlds[0][0] + w * 64;
    if (hi == 0) {
        Ltab[ln] = lsum_a;
        Ltab[32 + ln] = lsum_b;
    }
    F16* Elds = (F16*)&Klds[0][0] + w * 1152;   // [32 q][36] per wave
    const int q = ln;
#pragma unroll
    for (int set = 0; set < 2; ++set) {
        const f32x16 oacc = set ? oaccb : oacca;
#pragma unroll
        for (int r = 0; r < 16; ++r) {
            const int qr = (r & 3) + 8 * (r >> 2) + 4 * hi;
            const float invr = __builtin_amdgcn_rcpf(Ltab[set * 32 + qr]);
            Elds[qr * 36 + ln] = (F16)(oacc[r] * invr);
        }
        // O_t: [b][nb][t=h][kg][row][8]
        const int g = qpair * 256 + w * 64 + set * 32;   // block-local q base
        const int nb = s * 8 + (g >> 7);
        const int row0 = g & 127;
        F16* Ob = O + (size_t)b * 1048576 + nb * 32768 + h * 4096;
#pragma unroll
        for (int st = 0; st < 2; ++st) {
            const int kg = hi + 2 * st;
            const f16x8 ov = *(const f16x8*)&Elds[q * 36 + kg * 8];
            *(f16x8*)&Ob[kg * 1024 + (row0 + q) * 8] = ov;
        }
    }
}

// ---------------------------------------------------------------------------
// GEMM2 (R21): gemm1's 256j x 128n / 512-thread skeleton, K=256 (8 steps).
// Tiled linear staging both operands; direct f32 output stores.
// ---------------------------------------------------------------------------
__global__ __launch_bounds__(512, 4) void gemm2_kernel(
    const F16* __restrict__ A,      // We_t tiled [2][8][4][256][8]
    const F16* __restrict__ B,      // O_t tiled [b][32][8][4][128][8]
    const float* __restrict__ bias, // be [512]
    float* __restrict__ Y)          // [B][512][4096]
{
    const int b  = blockIdx.z;
    const int jb = blockIdx.y;               // 0..1
    const int j0 = jb * 256;
    const int nb = blockIdx.x;               // 0..31
    const int n0 = nb * 128;
    const int tid = threadIdx.x;
    const int w = tid >> 6, l = tid & 63;
    const int wr = w >> 1;          // 0..3 : j-wave
    const int wc = w & 1;           // 0..1 : n-wave
    const int cl = l & 15, rg = l >> 4;

    __shared__ __align__(16) char smem[49152];
    F16* Ash0 = (F16*)smem;
    F16* Ash1 = (F16*)(smem + 16384);
    F16* Bsh0 = (F16*)(smem + 32768);
    F16* Bsh1 = (F16*)(smem + 40960);

    f32x4 acc[4][4];
#pragma unroll
    for (int i = 0; i < 4; ++i)
#pragma unroll
        for (int j = 0; j < 4; ++j) acc[i][j] = (f32x4){0.f, 0.f, 0.f, 0.f};

    const F16* Abase = A + jb * 65536 + tid * 8;
    const F16* Bbase = B + (size_t)b * 1048576 + nb * 32768 + tid * 8;

#define G2_STAGE(Adst, Bdst, t)                                                \
    do {                                                                       \
        __builtin_amdgcn_global_load_lds(                                      \
            (const __attribute__((address_space(1))) void*)(Abase + (t) * 8192),\
            (__attribute__((address_space(3))) void*)&Adst[tid * 8], 16, 0, 0);\
        __builtin_amdgcn_global_load_lds(                                      \
            (const __attribute__((address_space(1))) void*)(Abase + (t) * 8192 \
                + 4096),                                                       \
            (__attribute__((address_space(3))) void*)&Adst[4096 + tid * 8],    \
            16, 0, 0);                                                         \
        __builtin_amdgcn_global_load_lds(                                      \
            (const __attribute__((address_space(1))) void*)(Bbase + (t) * 4096),\
            (__attribute__((address_space(3))) void*)&Bdst[tid * 8], 16, 0, 0);\
    } while (0)

    G2_STAGE(Ash0, Bsh0, 0);
    __syncthreads();

    for (int t = 0; t < 8; ++t) {
        F16* Ac = (t & 1) ? Ash1 : Ash0;
        F16* Bc = (t & 1) ? Bsh1 : Bsh0;
        if (t < 7) {
            F16* An = (t & 1) ? Ash0 : Ash1;
            F16* Bn = (t & 1) ? Bsh0 : Bsh1;
            G2_STAGE(An, Bn, t + 1);
        }
        f16x8 bf[4];
#pragma unroll
        for (int j = 0; j < 4; ++j)
            bf[j] = *(const f16x8*)&Bc[rg * 1024 + (wc * 64 + j * 16 + cl) * 8];
#pragma unroll
        for (int i = 0; i < 4; ++i) {
            const f16x8 af =
                *(const f16x8*)&Ac[rg * 2048 + (wr * 64 + i * 16 + cl) * 8];
#pragma unroll
            for (int j = 0; j < 4; ++j)
                acc[i][j] = __builtin_amdgcn_mfma_f32_16x16x32_f16(
                    af, bf[j], acc[i][j], 0, 0, 0);
        }
        __syncthreads();
    }
#undef G2_STAGE

#pragma unroll
    for (int i = 0; i < 4; ++i) {
        const int jj = j0 + wr * 64 + i * 16 + rg * 4;
#pragma unroll
        for (int j = 0; j < 4; ++j) {
            const int nn = n0 + wc * 64 + j * 16 + cl;
#pragma unroll
            for (int r = 0; r < 4; ++r)
                Y[((size_t)b * CIN + jj + r) * NTOK + nn] =
                    acc[i][j][r] + bias[jj + r];
        }
    }
}

// ---------------------------------------------------------------------------
// Workspace: Wc_t 786KB | bcomb 4KB | We_t 256KB | Qb 16.8MB | K_t 16.8MB |
// V_t 16.8MB | xt_t 33.5MB (O_t 16.8MB aliases xt_t after GEMM1). ~84.9 MB.
// ---------------------------------------------------------------------------
extern "C" void kernel_launch(void* const* d_in, const int* in_sizes, int n_in,
                              void* d_out, int out_size, void* d_ws, size_t ws_size,
                              hipStream_t stream)
{
    const float* x    = (const float*)d_in[0];
    const float* Wr   = (const float*)d_in[1];
    const float* br   = (const float*)d_in[2];
    const float* Wqkv = (const float*)d_in[3];
    const float* We   = (const float*)d_in[4];
    const float* be   = (const float*)d_in[5];
    float* out = (float*)d_out;

    char* ws = (char*)d_ws;
    F16*   Wc    = (F16*)ws;      ws += 786432;
    float* bcomb = (float*)ws;    ws += 4096;
    F16*   We_t  = (F16*)ws;      ws += 262144;
    F16*   Qb    = (F16*)ws;      ws += (size_t)BATCH * NTOK * 256 * 2;
    F16*   Kt    = (F16*)ws;      ws += (size_t)BATCH * NH * 4 * 32768 * 2;
    F16*   Vt    = (F16*)ws;      ws += (size_t)BATCH * NH * 4 * 32768 * 2;
    F16*   xt    = (F16*)ws;      // 33.5 MB (tiled)
    F16*   O_t   = (F16*)ws;      // aliases xt (16.8 MB), live after GEMM1

    fuse_weights_kernel<<<J3 / 2, 256, 0, stream>>>(Wr, br, Wqkv, Wc, bcomb);
    convert_we_kernel<<<CIN * CH / 256, 256, 0, stream>>>(We, We_t);
    transpose_convert_kernel<<<dim3(NTOK / 256, CIN / 8, BATCH), 256, 0, stream>>>(x, xt);
    gemm1_kernel<<<dim3(NTOK / 128, J3 / 256, BATCH), 512, 0, stream>>>(
        Wc, xt, bcomb, Qb, Kt, Vt);
    attn_mfma_kernel<<<1024, 256, 0, stream>>>(Qb, Kt, Vt, O_t);
    gemm2_kernel<<<dim3(NTOK / 128, CIN / 256, BATCH), 512, 0, stream>>>(
        We_t, O_t, be, out);
}